// Round 1
// baseline (471.525 us; speedup 1.0000x reference)
//
#include <hip/hip_runtime.h>
#include <hip/hip_bf16.h>

// Problem shape from setup_inputs(): B=256, N=512, adjacency fp32 [B,N,N].
// out[b,i,j] = dinv[b,i] * a_hat[b,i,j] * dinv[b,j]
//   a_hat = adjacency with diagonal replaced by atom_mask (rowsum != 0)
//   deg[b,i] = rowsum - diag + mask  (entries are 0/1 -> exact fp32)
//   dinv = deg > 0 ? 1/sqrt(deg) : 0
// Diagonal of output: dinv_i^2 * mask_i == dinv_i * 1.0f * dinv_i
// (mask=0 implies dinv=0), so pass 2 only needs to substitute a=1 on the diag.

#define NCOL 512   // N
#define NB   256   // B

// Pass 1: one 64-lane wave per row. Each lane loads 2 float4 (8 floats),
// reduce rowsum + diagonal value via butterfly shuffles across 64 lanes.
__global__ __launch_bounds__(256) void degree_kernel(
    const float* __restrict__ adj, float* __restrict__ dinv, int totalRows) {
    int gtid = blockIdx.x * blockDim.x + threadIdx.x;
    int row  = gtid >> 6;           // wave index == row index
    int lane = threadIdx.x & 63;
    if (row >= totalRows) return;

    const float4* r4 = (const float4*)(adj + (size_t)row * NCOL);
    float4 a0 = r4[lane];           // cols [lane*4, lane*4+4)
    float4 a1 = r4[lane + 64];      // cols [256+lane*4, ...)

    float s = (a0.x + a0.y) + (a0.z + a0.w) + (a1.x + a1.y) + (a1.z + a1.w);

    int i = row & (NCOL - 1);       // column index of the diagonal
    float diag = 0.0f;
    int j0 = lane << 2;
    if (i >= j0 && i < j0 + 4) {
        const float* p = (const float*)&a0;
        diag = p[i - j0];
    }
    int j1 = 256 + (lane << 2);
    if (i >= j1 && i < j1 + 4) {
        const float* p = (const float*)&a1;
        diag = p[i - j1];
    }

    #pragma unroll
    for (int off = 32; off > 0; off >>= 1) {
        s    += __shfl_xor(s, off);
        diag += __shfl_xor(diag, off);
    }

    if (lane == 0) {
        float mask = (s != 0.0f) ? 1.0f : 0.0f;
        float deg  = s - diag + mask;
        dinv[row]  = (deg > 0.0f) ? (1.0f / sqrtf(deg)) : 0.0f;
    }
}

// Pass 2: one thread per 4 output floats (float4 in/out).
__global__ __launch_bounds__(256) void scale_kernel(
    const float* __restrict__ adj, const float* __restrict__ dinv,
    float* __restrict__ out) {
    size_t idx4 = (size_t)blockIdx.x * blockDim.x + threadIdx.x;
    // N=512 -> 128 float4 per row
    int    j4   = (int)(idx4 & 127);
    size_t row  = idx4 >> 7;            // global row index in [0, B*N)
    int    i    = (int)(row & (NCOL - 1));
    size_t rowb = row & ~(size_t)(NCOL - 1);  // b*N

    float4 a  = ((const float4*)adj)[idx4];
    float4 dj = ((const float4*)(dinv + rowb))[j4];
    float  di = dinv[row];

    int j = j4 << 2;
    // reference order: (dinv_i * a_hat) * dinv_j
    float4 o;
    o.x = (di * ((j + 0 == i) ? 1.0f : a.x)) * dj.x;
    o.y = (di * ((j + 1 == i) ? 1.0f : a.y)) * dj.y;
    o.z = (di * ((j + 2 == i) ? 1.0f : a.z)) * dj.z;
    o.w = (di * ((j + 3 == i) ? 1.0f : a.w)) * dj.w;

    ((float4*)out)[idx4] = o;
}

extern "C" void kernel_launch(void* const* d_in, const int* in_sizes, int n_in,
                              void* d_out, int out_size, void* d_ws, size_t ws_size,
                              hipStream_t stream) {
    const float* adj = (const float*)d_in[0];
    float* out  = (float*)d_out;
    float* dinv = (float*)d_ws;          // B*N floats = 512 KiB

    const int totalRows = NB * NCOL;     // 131072

    // Pass 1: 1 wave/row, 4 waves/block -> totalRows/4 blocks
    degree_kernel<<<totalRows / 4, 256, 0, stream>>>(adj, dinv, totalRows);

    // Pass 2: B*N*N/4 float4 elements, 256 threads/block
    const size_t total4 = (size_t)NB * NCOL * NCOL / 4;   // 16,777,216
    scale_kernel<<<(unsigned)(total4 / 256), 256, 0, stream>>>(adj, dinv, out);
}